// Round 11
// baseline (295.203 us; speedup 1.0000x reference)
//
#include <hip/hip_runtime.h>
#include <cstdint>

#define DD 128
#define CAP 64
#define ESB 128          // fill blocks co-resident with pre-GEMM (swept: 128 optimal)
#define E0C 480000
#define E1C 96000
#define N0C 120000
#define N1C 30000
#define N2C 6000
#define ETOTC 3000000

typedef unsigned short u16;
typedef __attribute__((ext_vector_type(8))) short bf16x8;
typedef __attribute__((ext_vector_type(16))) float f32x16;

__device__ __forceinline__ u16 f2b(float f) {
    union { float f; unsigned u; } a; a.f = f;
    unsigned r = (a.u + 0x7fffu + ((a.u >> 16) & 1u)) >> 16;
    return (u16)r;
}
__device__ __forceinline__ float b2f(u16 u) {
    union { unsigned u; float f; } a; a.u = ((unsigned)u) << 16;
    return a.f;
}

// ---- K1: weight convert+transpose + zero counters + pack etype to 4-bit ----
// wt layout (shorts): mat*16384 + kc*2048 + t*512 + half*256 + l31*8 + j
// where n = t*32+l31, k = kc*16+half*8+j.
struct WtJob { const float* src[12]; };
__global__ __launch_bounds__(256) void prep_kernel(
    WtJob job, u16* __restrict__ dst, int* __restrict__ cnt0, int* __restrict__ cnt1,
    const int* __restrict__ etype, unsigned* __restrict__ r4)
{
    int gtid = blockIdx.x * 256 + threadIdx.x;
    for (int i = gtid; i < N1C + N2C; i += 256 * 256) {
        if (i < N1C) cnt0[i] = 0; else cnt1[i - N1C] = 0;
    }
    for (int i = gtid; i < ETOTC / 8; i += 256 * 256) {
        int4 a = ((const int4*)etype)[i * 2];
        int4 b = ((const int4*)etype)[i * 2 + 1];
        unsigned p = (unsigned)(a.x & 7) | ((unsigned)(a.y & 7) << 4)
                   | ((unsigned)(a.z & 7) << 8) | ((unsigned)(a.w & 7) << 12)
                   | ((unsigned)(b.x & 7) << 16) | ((unsigned)(b.y & 7) << 20)
                   | ((unsigned)(b.z & 7) << 24) | ((unsigned)(b.w & 7) << 28);
        r4[i] = p;
    }
    if (blockIdx.x >= 192) return;
    __shared__ float tile[32][33];
    int m = blockIdx.x >> 4;
    int t4 = blockIdx.x & 15;
    int tr = (t4 >> 2) * 32;   // k-base
    int tc = (t4 & 3) * 32;    // n-base
    int lx = threadIdx.x & 31, ly = threadIdx.x >> 5;
    #pragma unroll
    for (int yy = 0; yy < 32; yy += 8)
        tile[ly + yy][lx] = job.src[m][(tr + ly + yy) * DD + tc + lx];
    __syncthreads();
    int tid = threadIdx.x;
    if (tid < 128) {
        int nl = tid >> 2, kch = tid & 3;
        int k = tr + kch * 8, n = tc + nl;
        int kc = k >> 4, half = (k >> 3) & 1;
        int t = n >> 5, l31 = n & 31;
        bf16x8 pk;
        #pragma unroll
        for (int j = 0; j < 8; ++j) pk[j] = (short)f2b(tile[kch * 8 + j][nl]);
        *(bf16x8*)(dst + (size_t)m * 16384 + kc * 2048 + t * 512 + half * 256 + l31 * 8) = pk;
    }
}

// ================= shared device helpers (validated R7/R9) =================

__device__ __forceinline__ void fill_edges(
    int nblocks, int blockid,
    const int* __restrict__ src0, const int* __restrict__ dst0, const int* __restrict__ eid0,
    const int* __restrict__ src1, const int* __restrict__ dst1, const int* __restrict__ eid1,
    const unsigned* __restrict__ r4,
    int* __restrict__ cnt0, int* __restrict__ cnt1,
    int* __restrict__ ep0, int* __restrict__ ep1)
{
    const int STR = nblocks * 256;
    int gtid = blockid * 256 + threadIdx.x;
    int e = gtid;
    for (; e + 3 * STR < E0C + E1C; e += 4 * STR) {
        int d[4], eidv[4], s[4], r[4], pos[4];
        bool L0[4];
        #pragma unroll
        for (int u = 0; u < 4; ++u) {
            int idx = e + u * STR;
            L0[u] = idx < E0C;
            int ee = L0[u] ? idx : idx - E0C;
            d[u]    = L0[u] ? dst0[ee] : dst1[ee];
            eidv[u] = L0[u] ? eid0[ee] : eid1[ee];
            s[u]    = L0[u] ? src0[ee] : src1[ee];
        }
        #pragma unroll
        for (int u = 0; u < 4; ++u)
            r[u] = (int)((r4[eidv[u] >> 3] >> ((eidv[u] & 7) << 2)) & 7u);
        #pragma unroll
        for (int u = 0; u < 4; ++u)
            pos[u] = atomicAdd(L0[u] ? &cnt0[d[u]] : &cnt1[d[u]], 1);
        #pragma unroll
        for (int u = 0; u < 4; ++u) {
            if (pos[u] < CAP) {
                int* ep = L0[u] ? ep0 : ep1;
                ep[(size_t)d[u] * CAP + pos[u]] = s[u] | (r[u] << 28);
            }
        }
    }
    for (; e < E0C + E1C; e += STR) {
        bool L0 = e < E0C;
        int ee = L0 ? e : e - E0C;
        int d   = L0 ? dst0[ee] : dst1[ee];
        int eid = L0 ? eid0[ee] : eid1[ee];
        int s   = L0 ? src0[ee] : src1[ee];
        int r = (int)((r4[eid >> 3] >> ((eid & 7) << 2)) & 7u);
        int pos = atomicAdd(L0 ? &cnt0[d] : &cnt1[d], 1);
        if (pos < CAP) (L0 ? ep0 : ep1)[(size_t)d * CAP + pos] = s | (r << 28);
    }
}

__device__ __forceinline__ void pre_tile(
    const float* __restrict__ x, const u16* __restrict__ Wr,
    const float* __restrict__ bias, u16* __restrict__ h0, int m0, int lane)
{
    int l31 = lane & 31, half = lane >> 5;
    int arow = m0 + l31;
    const float* Aq = x + (size_t)arow * DD;
    float4 st[16];
    #pragma unroll
    for (int c = 0; c < 16; ++c)
        st[c] = *(const float4*)(Aq + ((c >> 1) * 16 + half * 8) + (c & 1) * 4);
    f32x16 accs[4];
    #pragma unroll
    for (int t = 0; t < 4; ++t)
        #pragma unroll
        for (int i = 0; i < 16; ++i) accs[t][i] = 0.f;
    #pragma unroll
    for (int kc = 0; kc < 8; ++kc) {
        bf16x8 bfr[4];
        #pragma unroll
        for (int t = 0; t < 4; ++t)
            bfr[t] = *(const bf16x8*)(Wr + (size_t)((kc * 4 + t) * 64 + lane) * 8);
        float4 u0 = st[2 * kc], u1 = st[2 * kc + 1];
        bf16x8 af;
        af[0] = (short)f2b(u0.x); af[1] = (short)f2b(u0.y);
        af[2] = (short)f2b(u0.z); af[3] = (short)f2b(u0.w);
        af[4] = (short)f2b(u1.x); af[5] = (short)f2b(u1.y);
        af[6] = (short)f2b(u1.z); af[7] = (short)f2b(u1.w);
        #pragma unroll
        for (int t = 0; t < 4; ++t)
            accs[t] = __builtin_amdgcn_mfma_f32_32x32x16_bf16(af, bfr[t], accs[t], 0, 0, 0);
    }
    float bb[4];
    #pragma unroll
    for (int t = 0; t < 4; ++t) bb[t] = bias[t * 32 + l31];
    #pragma unroll
    for (int reg = 0; reg < 16; ++reg) {
        int rl = (reg & 3) + 8 * (reg >> 2) + 4 * half;
        int row = m0 + rl;
        #pragma unroll
        for (int t = 0; t < 4; ++t)
            h0[(size_t)row * DD + t * 32 + l31] = f2b(fmaxf(accs[t][reg] + bb[t], 0.f));
    }
}

__device__ __forceinline__ void agg_row(
    const u16* __restrict__ h, const int* __restrict__ cnt,
    const int* __restrict__ ep, const float4* cmp4,
    u16* __restrict__ T, int ndst, int row, int lane)
{
    int n = cnt[row];
    int end = n < CAP ? n : CAP;
    const int* erow = ep + (size_t)row * CAP;
    float a0[4] = {0.f, 0.f, 0.f, 0.f};
    float a1[4] = {0.f, 0.f, 0.f, 0.f};
    int j = 0;
    for (; j + 16 <= end; j += 16) {
        int vv[16]; unsigned gg[16];
        #pragma unroll
        for (int u = 0; u < 16; ++u) vv[u] = erow[j + u];
        #pragma unroll
        for (int u = 0; u < 16; ++u)
            gg[u] = *(const unsigned*)(h + (size_t)(vv[u] & 0x0FFFFFFF) * DD + 2 * lane);
        #pragma unroll
        for (int u = 0; u < 16; ++u) {
            float4 c = cmp4[vv[u] >> 28];
            float x0 = b2f((u16)(gg[u] & 0xffffu));
            float x1 = b2f((u16)(gg[u] >> 16));
            a0[0] = fmaf(c.x, x0, a0[0]); a1[0] = fmaf(c.x, x1, a1[0]);
            a0[1] = fmaf(c.y, x0, a0[1]); a1[1] = fmaf(c.y, x1, a1[1]);
            a0[2] = fmaf(c.z, x0, a0[2]); a1[2] = fmaf(c.z, x1, a1[2]);
            a0[3] = fmaf(c.w, x0, a0[3]); a1[3] = fmaf(c.w, x1, a1[3]);
        }
    }
    for (; j + 4 <= end; j += 4) {
        int vv[4]; unsigned gg[4];
        #pragma unroll
        for (int u = 0; u < 4; ++u) vv[u] = erow[j + u];
        #pragma unroll
        for (int u = 0; u < 4; ++u)
            gg[u] = *(const unsigned*)(h + (size_t)(vv[u] & 0x0FFFFFFF) * DD + 2 * lane);
        #pragma unroll
        for (int u = 0; u < 4; ++u) {
            float4 c = cmp4[vv[u] >> 28];
            float x0 = b2f((u16)(gg[u] & 0xffffu));
            float x1 = b2f((u16)(gg[u] >> 16));
            a0[0] = fmaf(c.x, x0, a0[0]); a1[0] = fmaf(c.x, x1, a1[0]);
            a0[1] = fmaf(c.y, x0, a0[1]); a1[1] = fmaf(c.y, x1, a1[1]);
            a0[2] = fmaf(c.z, x0, a0[2]); a1[2] = fmaf(c.z, x1, a1[2]);
            a0[3] = fmaf(c.w, x0, a0[3]); a1[3] = fmaf(c.w, x1, a1[3]);
        }
    }
    for (; j < end; ++j) {
        int v = erow[j];
        unsigned g = *(const unsigned*)(h + (size_t)(v & 0x0FFFFFFF) * DD + 2 * lane);
        float4 c = cmp4[v >> 28];
        float x0 = b2f((u16)(g & 0xffffu));
        float x1 = b2f((u16)(g >> 16));
        a0[0] = fmaf(c.x, x0, a0[0]); a1[0] = fmaf(c.x, x1, a1[0]);
        a0[1] = fmaf(c.y, x0, a0[1]); a1[1] = fmaf(c.y, x1, a1[1]);
        a0[2] = fmaf(c.z, x0, a0[2]); a1[2] = fmaf(c.z, x1, a1[2]);
        a0[3] = fmaf(c.w, x0, a0[3]); a1[3] = fmaf(c.w, x1, a1[3]);
    }
    float inv = 1.f / fmaxf((float)n, 1.f);
    #pragma unroll
    for (int b = 0; b < 4; ++b) {
        unsigned pk = (unsigned)f2b(a0[b] * inv) | ((unsigned)f2b(a1[b] * inv) << 16);
        *(unsigned*)(T + ((size_t)b * ndst + row) * DD + 2 * lane) = pk;
    }
}

__device__ __forceinline__ void conv_tile_acc(
    const u16* __restrict__ Ap, const u16* __restrict__ Ar,
    const u16* __restrict__ Wp, const u16* __restrict__ Wr,
    int nrows, int m0, int lane, f32x16 acc[4])
{
    int l31 = lane & 31, half = lane >> 5;
    int arow = m0 + l31;
    bool rv = arow < nrows;
    #pragma unroll
    for (int t = 0; t < 4; ++t)
        #pragma unroll
        for (int i = 0; i < 16; ++i) acc[t][i] = 0.f;
    bf16x8 A0[8], A1[8];
    if (rv) {
        #pragma unroll
        for (int c = 0; c < 8; ++c)
            A0[c] = *(const bf16x8*)(Ap + (size_t)arow * DD + c * 16 + half * 8);
    } else {
        #pragma unroll
        for (int c = 0; c < 8; ++c) A0[c] = (bf16x8){0,0,0,0,0,0,0,0};
    }
    for (int p = 0; p <= 4; ++p) {
        const u16* Wsel = (p == 4) ? Wr : Wp + (size_t)p * 16384;
        if (p < 4) {
            const u16* An = (p + 1 == 4) ? Ar : Ap + (size_t)(p + 1) * nrows * DD;
            if (rv) {
                #pragma unroll
                for (int c = 0; c < 8; ++c)
                    A1[c] = *(const bf16x8*)(An + (size_t)arow * DD + c * 16 + half * 8);
            } else {
                #pragma unroll
                for (int c = 0; c < 8; ++c) A1[c] = (bf16x8){0,0,0,0,0,0,0,0};
            }
        }
        #pragma unroll
        for (int kc = 0; kc < 8; ++kc) {
            bf16x8 bfr[4];
            #pragma unroll
            for (int t = 0; t < 4; ++t)
                bfr[t] = *(const bf16x8*)(Wsel + (size_t)((kc * 4 + t) * 64 + lane) * 8);
            #pragma unroll
            for (int t = 0; t < 4; ++t)
                acc[t] = __builtin_amdgcn_mfma_f32_32x32x16_bf16(A0[kc], bfr[t], acc[t], 0, 0, 0);
        }
        if (p < 4) {
            #pragma unroll
            for (int c = 0; c < 8; ++c) A0[c] = A1[c];
        }
    }
}

__device__ __forceinline__ void gemm_ln_tile(
    const u16* __restrict__ Ap, const u16* __restrict__ Ar,
    const u16* __restrict__ Wp, const u16* __restrict__ Wr,
    const float* __restrict__ bias, const float* __restrict__ gwp,
    const float* __restrict__ bwp, u16* __restrict__ Cv, int nrows, int m0, int lane)
{
    int l31 = lane & 31, half = lane >> 5;
    f32x16 acc[4];
    conv_tile_acc(Ap, Ar, Wp, Wr, nrows, m0, lane, acc);
    float bb[4], gg[4], ww[4];
    #pragma unroll
    for (int t = 0; t < 4; ++t) {
        bb[t] = bias[t * 32 + l31];
        gg[t] = gwp[t * 32 + l31];
        ww[t] = bwp[t * 32 + l31];
    }
    #pragma unroll
    for (int reg = 0; reg < 16; ++reg) {
        int rl = (reg & 3) + 8 * (reg >> 2) + 4 * half;
        int row = m0 + rl;
        float v[4];
        #pragma unroll
        for (int t = 0; t < 4; ++t) v[t] = acc[t][reg] + bb[t];
        float s1 = 0.f, s2 = 0.f;
        #pragma unroll
        for (int t = 0; t < 4; ++t) { s1 += v[t]; s2 += v[t] * v[t]; }
        #pragma unroll
        for (int o = 1; o < 32; o <<= 1) {
            s1 += __shfl_xor(s1, o);
            s2 += __shfl_xor(s2, o);
        }
        float mu = s1 * (1.f / 128.f);
        float var = s2 * (1.f / 128.f) - mu * mu;
        float rstd = rsqrtf(fmaxf(var, 0.f) + 1e-5f);
        if (row < nrows) {
            #pragma unroll
            for (int t = 0; t < 4; ++t)
                Cv[(size_t)row * DD + t * 32 + l31] =
                    f2b(fmaxf((v[t] - mu) * rstd * gg[t] + ww[t], 0.f));
        }
    }
}

__device__ __forceinline__ void gemm_post_tile(
    const u16* __restrict__ Ap, const u16* __restrict__ Ar,
    const u16* __restrict__ Wp, const u16* __restrict__ Wr,
    const float* __restrict__ bias, const float* __restrict__ gwp,
    const float* __restrict__ bwp,
    const u16* __restrict__ Wpost, const float* __restrict__ postb,
    float* __restrict__ outp, int nrows, int m0, int lane, u16 (*lt)[136])
{
    int l31 = lane & 31, half = lane >> 5;
    f32x16 acc[4];
    conv_tile_acc(Ap, Ar, Wp, Wr, nrows, m0, lane, acc);
    float bb[4], gg[4], ww[4];
    #pragma unroll
    for (int t = 0; t < 4; ++t) {
        bb[t] = bias[t * 32 + l31];
        gg[t] = gwp[t * 32 + l31];
        ww[t] = bwp[t * 32 + l31];
    }
    #pragma unroll
    for (int reg = 0; reg < 16; ++reg) {
        int rl = (reg & 3) + 8 * (reg >> 2) + 4 * half;
        float v[4];
        #pragma unroll
        for (int t = 0; t < 4; ++t) v[t] = acc[t][reg] + bb[t];
        float s1 = 0.f, s2 = 0.f;
        #pragma unroll
        for (int t = 0; t < 4; ++t) { s1 += v[t]; s2 += v[t] * v[t]; }
        #pragma unroll
        for (int o = 1; o < 32; o <<= 1) {
            s1 += __shfl_xor(s1, o);
            s2 += __shfl_xor(s2, o);
        }
        float mu = s1 * (1.f / 128.f);
        float var = s2 * (1.f / 128.f) - mu * mu;
        float rstd = rsqrtf(fmaxf(var, 0.f) + 1e-5f);
        #pragma unroll
        for (int t = 0; t < 4; ++t)
            lt[rl][t * 32 + l31] = f2b(fmaxf((v[t] - mu) * rstd * gg[t] + ww[t], 0.f));
    }
    // wave-local LDS RAW fence
    asm volatile("s_waitcnt lgkmcnt(0)" ::: "memory");
    __builtin_amdgcn_sched_barrier(0);

    f32x16 acc2[4];
    #pragma unroll
    for (int t = 0; t < 4; ++t)
        #pragma unroll
        for (int i = 0; i < 16; ++i) acc2[t][i] = 0.f;
    bf16x8 A[8];
    #pragma unroll
    for (int c = 0; c < 8; ++c)
        A[c] = *(const bf16x8*)&lt[l31][c * 16 + half * 8];
    #pragma unroll
    for (int kc = 0; kc < 8; ++kc) {
        bf16x8 bfr[4];
        #pragma unroll
        for (int t = 0; t < 4; ++t)
            bfr[t] = *(const bf16x8*)(Wpost + (size_t)((kc * 4 + t) * 64 + lane) * 8);
        #pragma unroll
        for (int t = 0; t < 4; ++t)
            acc2[t] = __builtin_amdgcn_mfma_f32_32x32x16_bf16(A[kc], bfr[t], acc2[t], 0, 0, 0);
    }
    float pb[4];
    #pragma unroll
    for (int t = 0; t < 4; ++t) pb[t] = postb[t * 32 + l31];
    #pragma unroll
    for (int reg = 0; reg < 16; ++reg) {
        int rl = (reg & 3) + 8 * (reg >> 2) + 4 * half;
        int row = m0 + rl;
        if (row < nrows) {
            #pragma unroll
            for (int t = 0; t < 4; ++t)
                outp[(size_t)row * DD + t * 32 + l31] = acc2[t][reg] + pb[t];
        }
    }
}

// ================= kernels (R7 structure, session best: 275.1 µs) =================

__global__ __launch_bounds__(256) void fillpre_kernel(
    const float* __restrict__ x,
    const int* __restrict__ src0, const int* __restrict__ dst0, const int* __restrict__ eid0,
    const int* __restrict__ src1, const int* __restrict__ dst1, const int* __restrict__ eid1,
    const unsigned* __restrict__ r4,
    int* __restrict__ cnt0, int* __restrict__ cnt1,
    int* __restrict__ ep0, int* __restrict__ ep1,
    const u16* __restrict__ Wr, const float* __restrict__ bias,
    u16* __restrict__ h0)
{
    if (blockIdx.x < ESB) {
        fill_edges(ESB, blockIdx.x, src0, dst0, eid0, src1, dst1, eid1,
                   r4, cnt0, cnt1, ep0, ep1);
        return;
    }
    int bid = blockIdx.x - ESB;
    int wave = threadIdx.x >> 6, lane = threadIdx.x & 63;
    int m0 = (bid * 4 + wave) * 32;
    if (m0 >= N0C) return;
    pre_tile(x, Wr, bias, h0, m0, lane);
}

__global__ __launch_bounds__(256) void agg_kernel(
    const u16* __restrict__ h, const int* __restrict__ cnt,
    const int* __restrict__ ep, const float* __restrict__ comp,
    u16* __restrict__ T, int ndst)
{
    __shared__ float4 cmp4[8];
    if (threadIdx.x < 8) cmp4[threadIdx.x] = ((const float4*)comp)[threadIdx.x];
    __syncthreads();
    int row = blockIdx.x * 4 + (threadIdx.x >> 6);
    if (row >= ndst) return;
    agg_row(h, cnt, ep, cmp4, T, ndst, row, threadIdx.x & 63);
}

__global__ __launch_bounds__(64) void mfma_gemm_ln(
    const u16* __restrict__ Ap, const u16* __restrict__ Ar,
    const u16* __restrict__ Wp, const u16* __restrict__ Wr,
    const float* __restrict__ bias, const float* __restrict__ gw,
    const float* __restrict__ bw, u16* __restrict__ Cv, int nrows)
{
    gemm_ln_tile(Ap, Ar, Wp, Wr, bias, gw, bw, Cv, nrows,
                 blockIdx.x * 32, threadIdx.x & 63);
}

__global__ __launch_bounds__(64) void gemm_post_kernel(
    const u16* __restrict__ Ap, const u16* __restrict__ Ar,
    const u16* __restrict__ Wp, const u16* __restrict__ Wr,
    const float* __restrict__ bias, const float* __restrict__ gw,
    const float* __restrict__ bw,
    const u16* __restrict__ Wpost, const float* __restrict__ postb,
    float* __restrict__ outp, int nrows)
{
    __shared__ u16 lt[32][136];
    gemm_post_tile(Ap, Ar, Wp, Wr, bias, gw, bw, Wpost, postb, outp, nrows,
                   blockIdx.x * 32, threadIdx.x & 63, lt);
}

extern "C" void kernel_launch(void* const* d_in, const int* in_sizes, int n_in,
                              void* d_out, int out_size, void* d_ws, size_t ws_size,
                              hipStream_t stream)
{
    const float* x     = (const float*)d_in[0];
    const int* src0    = (const int*)d_in[1];
    const int* dst0    = (const int*)d_in[2];
    const int* eid0    = (const int*)d_in[3];
    const int* src1    = (const int*)d_in[4];
    const int* dst1    = (const int*)d_in[5];
    const int* eid1    = (const int*)d_in[6];
    const int* etype   = (const int*)d_in[7];
    const float* preW  = (const float*)d_in[8];
    const float* preb  = (const float*)d_in[9];
    const float* basis0 = (const float*)d_in[10];
    const float* comp0  = (const float*)d_in[11];
    const float* root0  = (const float*)d_in[12];
    const float* bias0  = (const float*)d_in[13];
    const float* g0    = (const float*)d_in[14];
    const float* be0   = (const float*)d_in[15];
    const float* basis1 = (const float*)d_in[16];
    const float* comp1  = (const float*)d_in[17];
    const float* root1  = (const float*)d_in[18];
    const float* bias1  = (const float*)d_in[19];
    const float* g1    = (const float*)d_in[20];
    const float* be1   = (const float*)d_in[21];
    const float* postW = (const float*)d_in[22];
    const float* postb = (const float*)d_in[23];
    float* out = (float*)d_out;

    char* ws = (char*)d_ws;
    size_t o = 0;
    auto alloc = [&](size_t bytes) { char* p = ws + o; o += (bytes + 255) & ~(size_t)255; return p; };
    u16* h0   = (u16*)alloc((size_t)N0C * DD * 2);
    u16* T0   = (u16*)alloc((size_t)4 * N1C * DD * 2);
    u16* h1   = (u16*)alloc((size_t)N1C * DD * 2);
    u16* T1   = (u16*)alloc((size_t)4 * N2C * DD * 2);
    u16* wt   = (u16*)alloc((size_t)12 * 16384 * 2);
    int* cnt0 = (int*)alloc((size_t)N1C * 4);
    int* cnt1 = (int*)alloc((size_t)N2C * 4);
    int* ep0  = (int*)alloc((size_t)N1C * CAP * 4);
    int* ep1  = (int*)alloc((size_t)N2C * CAP * 4);
    unsigned* r4 = (unsigned*)alloc((size_t)(ETOTC / 8) * 4);

    // wt layout: [0]=pre, [1..4]=basis0, [5]=root0, [6..9]=basis1, [10]=root1, [11]=post
    WtJob job;
    job.src[0] = preW;
    for (int b = 0; b < 4; ++b) job.src[1 + b] = basis0 + (size_t)b * 16384;
    job.src[5] = root0;
    for (int b = 0; b < 4; ++b) job.src[6 + b] = basis1 + (size_t)b * 16384;
    job.src[10] = root1;
    job.src[11] = postW;

    // K1: weight transpose + zero counters + etype nibble-pack
    prep_kernel<<<256, 256, 0, stream>>>(job, wt, cnt0, cnt1, etype, r4);
    // K2: fused fill (128 blocks) + pre-GEMM (938 blocks)
    fillpre_kernel<<<ESB + (N0C + 127) / 128, 256, 0, stream>>>(
        x, src0, dst0, eid0, src1, dst1, eid1, r4,
        cnt0, cnt1, ep0, ep1, wt + 0 * 16384, preb, h0);
    // K3: agg layer 0 (1 row/wave)
    agg_kernel<<<(N1C + 3) / 4, 256, 0, stream>>>(h0, cnt0, ep0, comp0, T0, N1C);
    // K4: conv0 + LN + ReLU
    mfma_gemm_ln<<<(N1C + 31) / 32, 64, 0, stream>>>(
        T0, h0, wt + 1 * 16384, wt + 5 * 16384, bias0, g0, be0, h1, N1C);
    // K5: agg layer 1
    agg_kernel<<<(N2C + 3) / 4, 256, 0, stream>>>(h1, cnt1, ep1, comp1, T1, N2C);
    // K6: conv1 + LN + ReLU + post-GEMM (writes float out directly)
    gemm_post_kernel<<<(N2C + 31) / 32, 64, 0, stream>>>(
        T1, h1, wt + 6 * 16384, wt + 10 * 16384, bias1, g1, be1,
        wt + 11 * 16384, postb, out, N2C);
}

// Round 12
// 273.155 us; speedup vs baseline: 1.0807x; 1.0807x over previous
//
#include <hip/hip_runtime.h>
#include <cstdint>

#define DD 128
#define CAP 64
#define ESB 128          // edge-fill blocks co-resident with pre-GEMM blocks
#define E0C 480000
#define E1C 96000
#define N0C 120000
#define N1C 30000
#define N2C 6000
#define ETOTC 3000000

typedef unsigned short u16;
typedef __attribute__((ext_vector_type(8))) short bf16x8;
typedef __attribute__((ext_vector_type(16))) float f32x16;

__device__ __forceinline__ u16 f2b(float f) {
    union { float f; unsigned u; } a; a.f = f;
    unsigned r = (a.u + 0x7fffu + ((a.u >> 16) & 1u)) >> 16;
    return (u16)r;
}
__device__ __forceinline__ float b2f(u16 u) {
    union { unsigned u; float f; } a; a.u = ((unsigned)u) << 16;
    return a.f;
}

// ---- K1: weight convert+transpose + zero counters + pack etype to 4-bit ----
// wt layout (shorts): mat*16384 + kc*2048 + t*512 + half*256 + l31*8 + j
// where n = t*32+l31, k = kc*16+half*8+j.
struct WtJob { const float* src[12]; };
__global__ __launch_bounds__(256) void prep_kernel(
    WtJob job, u16* __restrict__ dst, int* __restrict__ cnt0, int* __restrict__ cnt1,
    const int* __restrict__ etype, unsigned* __restrict__ r4)
{
    int gtid = blockIdx.x * 256 + threadIdx.x;
    for (int i = gtid; i < N1C + N2C; i += 256 * 256) {
        if (i < N1C) cnt0[i] = 0; else cnt1[i - N1C] = 0;
    }
    for (int i = gtid; i < ETOTC / 8; i += 256 * 256) {
        int4 a = ((const int4*)etype)[i * 2];
        int4 b = ((const int4*)etype)[i * 2 + 1];
        unsigned p = (unsigned)(a.x & 7) | ((unsigned)(a.y & 7) << 4)
                   | ((unsigned)(a.z & 7) << 8) | ((unsigned)(a.w & 7) << 12)
                   | ((unsigned)(b.x & 7) << 16) | ((unsigned)(b.y & 7) << 20)
                   | ((unsigned)(b.z & 7) << 24) | ((unsigned)(b.w & 7) << 28);
        r4[i] = p;
    }
    if (blockIdx.x >= 192) return;
    __shared__ float tile[32][33];
    int m = blockIdx.x >> 4;
    int t4 = blockIdx.x & 15;
    int tr = (t4 >> 2) * 32;   // k-base
    int tc = (t4 & 3) * 32;    // n-base
    int lx = threadIdx.x & 31, ly = threadIdx.x >> 5;
    #pragma unroll
    for (int yy = 0; yy < 32; yy += 8)
        tile[ly + yy][lx] = job.src[m][(tr + ly + yy) * DD + tc + lx];
    __syncthreads();
    int tid = threadIdx.x;
    if (tid < 128) {
        int nl = tid >> 2, kch = tid & 3;
        int k = tr + kch * 8, n = tc + nl;
        int kc = k >> 4, half = (k >> 3) & 1;
        int t = n >> 5, l31 = n & 31;
        bf16x8 pk;
        #pragma unroll
        for (int j = 0; j < 8; ++j) pk[j] = (short)f2b(tile[kch * 8 + j][nl]);
        *(bf16x8*)(dst + (size_t)m * 16384 + kc * 2048 + t * 512 + half * 256 + l31 * 8) = pk;
    }
}

// ---- K2: FUSED edge fill (4-way batched, compile-time stride) + pre-GEMM ----
// Blocks [0, ESB): latency-bound batched fill, ONE pass over the edges,
// type lookup via the 1.5 MB nibble table (saves ~25 MB of gather fetch).
// Blocks [ESB, ...): pre-GEMM h0 = relu(x @ preW + preb) — BW-bound.
// Co-residency overlaps the two. NOTE: fill body kept INLINE with the
// compile-time ESB stride — refactoring it into a helper with runtime
// nblocks dropped VGPR 84->64 and cost +11 µs (R10/R11 regression).
__global__ __launch_bounds__(256) void fillpre_kernel(
    const float* __restrict__ x,
    const int* __restrict__ src0, const int* __restrict__ dst0, const int* __restrict__ eid0,
    const int* __restrict__ src1, const int* __restrict__ dst1, const int* __restrict__ eid1,
    const unsigned* __restrict__ r4,
    int* __restrict__ cnt0, int* __restrict__ cnt1,
    int* __restrict__ ep0, int* __restrict__ ep1,
    const u16* __restrict__ Wr, const float* __restrict__ bias,
    u16* __restrict__ h0)
{
    if (blockIdx.x < ESB) {
        const int STR = ESB * 256;
        int gtid = blockIdx.x * 256 + threadIdx.x;
        int e = gtid;
        for (; e + 3 * STR < E0C + E1C; e += 4 * STR) {
            int d[4], eidv[4], s[4], r[4], pos[4];
            bool L0[4];
            #pragma unroll
            for (int u = 0; u < 4; ++u) {
                int idx = e + u * STR;
                L0[u] = idx < E0C;
                int ee = L0[u] ? idx : idx - E0C;
                d[u]    = L0[u] ? dst0[ee] : dst1[ee];
                eidv[u] = L0[u] ? eid0[ee] : eid1[ee];
                s[u]    = L0[u] ? src0[ee] : src1[ee];
            }
            #pragma unroll
            for (int u = 0; u < 4; ++u)
                r[u] = (int)((r4[eidv[u] >> 3] >> ((eidv[u] & 7) << 2)) & 7u);
            #pragma unroll
            for (int u = 0; u < 4; ++u)
                pos[u] = atomicAdd(L0[u] ? &cnt0[d[u]] : &cnt1[d[u]], 1);
            #pragma unroll
            for (int u = 0; u < 4; ++u) {
                if (pos[u] < CAP) {
                    int* ep = L0[u] ? ep0 : ep1;
                    ep[(size_t)d[u] * CAP + pos[u]] = s[u] | (r[u] << 28);
                }
            }
        }
        for (; e < E0C + E1C; e += STR) {
            bool L0 = e < E0C;
            int ee = L0 ? e : e - E0C;
            int d   = L0 ? dst0[ee] : dst1[ee];
            int eid = L0 ? eid0[ee] : eid1[ee];
            int s   = L0 ? src0[ee] : src1[ee];
            int r = (int)((r4[eid >> 3] >> ((eid & 7) << 2)) & 7u);
            int pos = atomicAdd(L0 ? &cnt0[d] : &cnt1[d], 1);
            if (pos < CAP) (L0 ? ep0 : ep1)[(size_t)d * CAP + pos] = s | (r << 28);
        }
        return;
    }

    // ---- pre-GEMM: one 32-row tile per wave ----
    int bid = blockIdx.x - ESB;
    int wave = threadIdx.x >> 6;
    int lane = threadIdx.x & 63;
    int l31 = lane & 31, half = lane >> 5;
    int m0 = (bid * 4 + wave) * 32;
    if (m0 >= N0C) return;
    int arow = m0 + l31;
    bool rv = arow < N0C;

    const float* Aq = x + (size_t)arow * DD;
    float4 st[16];
    if (rv) {
        #pragma unroll
        for (int c = 0; c < 16; ++c)
            st[c] = *(const float4*)(Aq + ((c >> 1) * 16 + half * 8) + (c & 1) * 4);
    } else {
        #pragma unroll
        for (int c = 0; c < 16; ++c) st[c] = make_float4(0.f, 0.f, 0.f, 0.f);
    }
    f32x16 accs[4];
    #pragma unroll
    for (int t = 0; t < 4; ++t)
        #pragma unroll
        for (int i = 0; i < 16; ++i) accs[t][i] = 0.f;
    #pragma unroll
    for (int kc = 0; kc < 8; ++kc) {
        bf16x8 bfr[4];
        #pragma unroll
        for (int t = 0; t < 4; ++t)
            bfr[t] = *(const bf16x8*)(Wr + (size_t)((kc * 4 + t) * 64 + lane) * 8);
        float4 u0 = st[2 * kc], u1 = st[2 * kc + 1];
        bf16x8 af;
        af[0] = (short)f2b(u0.x); af[1] = (short)f2b(u0.y);
        af[2] = (short)f2b(u0.z); af[3] = (short)f2b(u0.w);
        af[4] = (short)f2b(u1.x); af[5] = (short)f2b(u1.y);
        af[6] = (short)f2b(u1.z); af[7] = (short)f2b(u1.w);
        #pragma unroll
        for (int t = 0; t < 4; ++t)
            accs[t] = __builtin_amdgcn_mfma_f32_32x32x16_bf16(af, bfr[t], accs[t], 0, 0, 0);
    }
    float bb[4];
    #pragma unroll
    for (int t = 0; t < 4; ++t) bb[t] = bias[t * 32 + l31];
    #pragma unroll
    for (int reg = 0; reg < 16; ++reg) {
        int rl = (reg & 3) + 8 * (reg >> 2) + 4 * half;
        int row = m0 + rl;
        if (row < N0C) {
            #pragma unroll
            for (int t = 0; t < 4; ++t)
                h0[(size_t)row * DD + t * 32 + l31] =
                    f2b(fmaxf(accs[t][reg] + bb[t], 0.f));
        }
    }
}

// ---- K3/K5: gather-aggregate into 4 basis planes, 1 row per wave ----
__global__ __launch_bounds__(256) void agg_kernel(
    const u16* __restrict__ h, const int* __restrict__ cnt,
    const int* __restrict__ ep, const float* __restrict__ comp,
    u16* __restrict__ T, int ndst)
{
    __shared__ float4 cmp4[8];
    if (threadIdx.x < 8) cmp4[threadIdx.x] = ((const float4*)comp)[threadIdx.x];
    __syncthreads();
    int row = blockIdx.x * 4 + (threadIdx.x >> 6);
    if (row >= ndst) return;
    int lane = threadIdx.x & 63;
    int n = cnt[row];
    int end = n < CAP ? n : CAP;
    const int* erow = ep + (size_t)row * CAP;
    float a0[4] = {0.f, 0.f, 0.f, 0.f};
    float a1[4] = {0.f, 0.f, 0.f, 0.f};
    int j = 0;
    for (; j + 16 <= end; j += 16) {
        int vv[16]; unsigned gg[16];
        #pragma unroll
        for (int u = 0; u < 16; ++u) vv[u] = erow[j + u];
        #pragma unroll
        for (int u = 0; u < 16; ++u)
            gg[u] = *(const unsigned*)(h + (size_t)(vv[u] & 0x0FFFFFFF) * DD + 2 * lane);
        #pragma unroll
        for (int u = 0; u < 16; ++u) {
            float4 c = cmp4[vv[u] >> 28];
            float x0 = b2f((u16)(gg[u] & 0xffffu));
            float x1 = b2f((u16)(gg[u] >> 16));
            a0[0] = fmaf(c.x, x0, a0[0]); a1[0] = fmaf(c.x, x1, a1[0]);
            a0[1] = fmaf(c.y, x0, a0[1]); a1[1] = fmaf(c.y, x1, a1[1]);
            a0[2] = fmaf(c.z, x0, a0[2]); a1[2] = fmaf(c.z, x1, a1[2]);
            a0[3] = fmaf(c.w, x0, a0[3]); a1[3] = fmaf(c.w, x1, a1[3]);
        }
    }
    for (; j + 4 <= end; j += 4) {
        int vv[4]; unsigned gg[4];
        #pragma unroll
        for (int u = 0; u < 4; ++u) vv[u] = erow[j + u];
        #pragma unroll
        for (int u = 0; u < 4; ++u)
            gg[u] = *(const unsigned*)(h + (size_t)(vv[u] & 0x0FFFFFFF) * DD + 2 * lane);
        #pragma unroll
        for (int u = 0; u < 4; ++u) {
            float4 c = cmp4[vv[u] >> 28];
            float x0 = b2f((u16)(gg[u] & 0xffffu));
            float x1 = b2f((u16)(gg[u] >> 16));
            a0[0] = fmaf(c.x, x0, a0[0]); a1[0] = fmaf(c.x, x1, a1[0]);
            a0[1] = fmaf(c.y, x0, a0[1]); a1[1] = fmaf(c.y, x1, a1[1]);
            a0[2] = fmaf(c.z, x0, a0[2]); a1[2] = fmaf(c.z, x1, a1[2]);
            a0[3] = fmaf(c.w, x0, a0[3]); a1[3] = fmaf(c.w, x1, a1[3]);
        }
    }
    for (; j < end; ++j) {
        int v = erow[j];
        unsigned g = *(const unsigned*)(h + (size_t)(v & 0x0FFFFFFF) * DD + 2 * lane);
        float4 c = cmp4[v >> 28];
        float x0 = b2f((u16)(g & 0xffffu));
        float x1 = b2f((u16)(g >> 16));
        a0[0] = fmaf(c.x, x0, a0[0]); a1[0] = fmaf(c.x, x1, a1[0]);
        a0[1] = fmaf(c.y, x0, a0[1]); a1[1] = fmaf(c.y, x1, a1[1]);
        a0[2] = fmaf(c.z, x0, a0[2]); a1[2] = fmaf(c.z, x1, a1[2]);
        a0[3] = fmaf(c.w, x0, a0[3]); a1[3] = fmaf(c.w, x1, a1[3]);
    }
    float inv = 1.f / fmaxf((float)n, 1.f);
    #pragma unroll
    for (int b = 0; b < 4; ++b) {
        unsigned pk = (unsigned)f2b(a0[b] * inv) | ((unsigned)f2b(a1[b] * inv) << 16);
        *(unsigned*)(T + ((size_t)b * ndst + row) * DD + 2 * lane) = pk;
    }
}

// ---- K4: 5-plane MFMA GEMM + LN + ReLU, bf16 out (conv0) ----
// C/D layout: col=lane&31, row=(reg&3)+8*(reg>>2)+4*(lane>>5)  [m74/m101].
__global__ __launch_bounds__(64) void mfma_gemm_ln(
    const u16* __restrict__ Ap, const u16* __restrict__ Ar,
    const u16* __restrict__ Wp, const u16* __restrict__ Wr,
    const float* __restrict__ bias, const float* __restrict__ gw,
    const float* __restrict__ bw, u16* __restrict__ Cv, int nrows)
{
    int lane = threadIdx.x & 63;
    int l31 = lane & 31, half = lane >> 5;
    int m0 = blockIdx.x * 32;
    int arow = m0 + l31;
    bool rv = arow < nrows;
    f32x16 acc[4];
    #pragma unroll
    for (int t = 0; t < 4; ++t)
        #pragma unroll
        for (int i = 0; i < 16; ++i) acc[t][i] = 0.f;

    bf16x8 A0[8], A1[8];
    if (rv) {
        #pragma unroll
        for (int c = 0; c < 8; ++c)
            A0[c] = *(const bf16x8*)(Ap + (size_t)arow * DD + c * 16 + half * 8);
    } else {
        #pragma unroll
        for (int c = 0; c < 8; ++c) A0[c] = (bf16x8){0,0,0,0,0,0,0,0};
    }
    for (int p = 0; p <= 4; ++p) {
        const u16* Wsel = (p == 4) ? Wr : Wp + (size_t)p * 16384;
        if (p < 4) {
            const u16* An = (p + 1 == 4) ? Ar : Ap + (size_t)(p + 1) * nrows * DD;
            if (rv) {
                #pragma unroll
                for (int c = 0; c < 8; ++c)
                    A1[c] = *(const bf16x8*)(An + (size_t)arow * DD + c * 16 + half * 8);
            } else {
                #pragma unroll
                for (int c = 0; c < 8; ++c) A1[c] = (bf16x8){0,0,0,0,0,0,0,0};
            }
        }
        #pragma unroll
        for (int kc = 0; kc < 8; ++kc) {
            bf16x8 bfr[4];
            #pragma unroll
            for (int t = 0; t < 4; ++t)
                bfr[t] = *(const bf16x8*)(Wsel + (size_t)((kc * 4 + t) * 64 + lane) * 8);
            #pragma unroll
            for (int t = 0; t < 4; ++t)
                acc[t] = __builtin_amdgcn_mfma_f32_32x32x16_bf16(A0[kc], bfr[t], acc[t], 0, 0, 0);
        }
        if (p < 4) {
            #pragma unroll
            for (int c = 0; c < 8; ++c) A0[c] = A1[c];
        }
    }

    float bb[4], gg[4], ww[4];
    #pragma unroll
    for (int t = 0; t < 4; ++t) {
        bb[t] = bias[t * 32 + l31];
        gg[t] = gw[t * 32 + l31];
        ww[t] = bw[t * 32 + l31];
    }
    #pragma unroll
    for (int reg = 0; reg < 16; ++reg) {
        int rl = (reg & 3) + 8 * (reg >> 2) + 4 * half;
        int row = m0 + rl;
        float v[4];
        #pragma unroll
        for (int t = 0; t < 4; ++t) v[t] = acc[t][reg] + bb[t];
        float s1 = 0.f, s2 = 0.f;
        #pragma unroll
        for (int t = 0; t < 4; ++t) { s1 += v[t]; s2 += v[t] * v[t]; }
        #pragma unroll
        for (int o = 1; o < 32; o <<= 1) {
            s1 += __shfl_xor(s1, o);
            s2 += __shfl_xor(s2, o);
        }
        float mu = s1 * (1.f / 128.f);
        float var = s2 * (1.f / 128.f) - mu * mu;
        float rstd = rsqrtf(fmaxf(var, 0.f) + 1e-5f);
        if (row < nrows) {
            #pragma unroll
            for (int t = 0; t < 4; ++t)
                Cv[(size_t)row * DD + t * 32 + l31] =
                    f2b(fmaxf((v[t] - mu) * rstd * gg[t] + ww[t], 0.f));
        }
    }
}

// ---- K6: conv1 + LN + ReLU + post-GEMM fused ----
__global__ __launch_bounds__(64) void gemm_post_kernel(
    const u16* __restrict__ Ap, const u16* __restrict__ Ar,
    const u16* __restrict__ Wp, const u16* __restrict__ Wr,
    const float* __restrict__ bias, const float* __restrict__ gw,
    const float* __restrict__ bw,
    const u16* __restrict__ Wpost, const float* __restrict__ postb,
    float* __restrict__ outp, int nrows)
{
    __shared__ u16 lt[32][136];   // 272B row stride: 16B-aligned, conflict-reduced
    int lane = threadIdx.x & 63;
    int l31 = lane & 31, half = lane >> 5;
    int m0 = blockIdx.x * 32;
    int arow = m0 + l31;
    bool rv = arow < nrows;
    f32x16 acc[4];
    #pragma unroll
    for (int t = 0; t < 4; ++t)
        #pragma unroll
        for (int i = 0; i < 16; ++i) acc[t][i] = 0.f;

    bf16x8 A0[8], A1[8];
    if (rv) {
        #pragma unroll
        for (int c = 0; c < 8; ++c)
            A0[c] = *(const bf16x8*)(Ap + (size_t)arow * DD + c * 16 + half * 8);
    } else {
        #pragma unroll
        for (int c = 0; c < 8; ++c) A0[c] = (bf16x8){0,0,0,0,0,0,0,0};
    }
    for (int p = 0; p <= 4; ++p) {
        const u16* Wsel = (p == 4) ? Wr : Wp + (size_t)p * 16384;
        if (p < 4) {
            const u16* An = (p + 1 == 4) ? Ar : Ap + (size_t)(p + 1) * nrows * DD;
            if (rv) {
                #pragma unroll
                for (int c = 0; c < 8; ++c)
                    A1[c] = *(const bf16x8*)(An + (size_t)arow * DD + c * 16 + half * 8);
            } else {
                #pragma unroll
                for (int c = 0; c < 8; ++c) A1[c] = (bf16x8){0,0,0,0,0,0,0,0};
            }
        }
        #pragma unroll
        for (int kc = 0; kc < 8; ++kc) {
            bf16x8 bfr[4];
            #pragma unroll
            for (int t = 0; t < 4; ++t)
                bfr[t] = *(const bf16x8*)(Wsel + (size_t)((kc * 4 + t) * 64 + lane) * 8);
            #pragma unroll
            for (int t = 0; t < 4; ++t)
                acc[t] = __builtin_amdgcn_mfma_f32_32x32x16_bf16(A0[kc], bfr[t], acc[t], 0, 0, 0);
        }
        if (p < 4) {
            #pragma unroll
            for (int c = 0; c < 8; ++c) A0[c] = A1[c];
        }
    }

    // LN + ReLU -> LDS tile (bf16)
    float bb[4], gg[4], ww[4];
    #pragma unroll
    for (int t = 0; t < 4; ++t) {
        bb[t] = bias[t * 32 + l31];
        gg[t] = gw[t * 32 + l31];
        ww[t] = bw[t * 32 + l31];
    }
    #pragma unroll
    for (int reg = 0; reg < 16; ++reg) {
        int rl = (reg & 3) + 8 * (reg >> 2) + 4 * half;
        float v[4];
        #pragma unroll
        for (int t = 0; t < 4; ++t) v[t] = acc[t][reg] + bb[t];
        float s1 = 0.f, s2 = 0.f;
        #pragma unroll
        for (int t = 0; t < 4; ++t) { s1 += v[t]; s2 += v[t] * v[t]; }
        #pragma unroll
        for (int o = 1; o < 32; o <<= 1) {
            s1 += __shfl_xor(s1, o);
            s2 += __shfl_xor(s2, o);
        }
        float mu = s1 * (1.f / 128.f);
        float var = s2 * (1.f / 128.f) - mu * mu;
        float rstd = rsqrtf(fmaxf(var, 0.f) + 1e-5f);
        #pragma unroll
        for (int t = 0; t < 4; ++t)
            lt[rl][t * 32 + l31] = f2b(fmaxf((v[t] - mu) * rstd * gg[t] + ww[t], 0.f));
    }
    __syncthreads();   // single-wave block: cheap fence for the LDS transpose

    // post GEMM: A row l31 from LDS, one plane
    f32x16 acc2[4];
    #pragma unroll
    for (int t = 0; t < 4; ++t)
        #pragma unroll
        for (int i = 0; i < 16; ++i) acc2[t][i] = 0.f;
    bf16x8 A[8];
    #pragma unroll
    for (int c = 0; c < 8; ++c)
        A[c] = *(const bf16x8*)&lt[l31][c * 16 + half * 8];
    #pragma unroll
    for (int kc = 0; kc < 8; ++kc) {
        bf16x8 bfr[4];
        #pragma unroll
        for (int t = 0; t < 4; ++t)
            bfr[t] = *(const bf16x8*)(Wpost + (size_t)((kc * 4 + t) * 64 + lane) * 8);
        #pragma unroll
        for (int t = 0; t < 4; ++t)
            acc2[t] = __builtin_amdgcn_mfma_f32_32x32x16_bf16(A[kc], bfr[t], acc2[t], 0, 0, 0);
    }
    float pb[4];
    #pragma unroll
    for (int t = 0; t < 4; ++t) pb[t] = postb[t * 32 + l31];
    #pragma unroll
    for (int reg = 0; reg < 16; ++reg) {
        int rl = (reg & 3) + 8 * (reg >> 2) + 4 * half;
        int row = m0 + rl;
        if (row < nrows) {
            #pragma unroll
            for (int t = 0; t < 4; ++t)
                outp[(size_t)row * DD + t * 32 + l31] = acc2[t][reg] + pb[t];
        }
    }
}

extern "C" void kernel_launch(void* const* d_in, const int* in_sizes, int n_in,
                              void* d_out, int out_size, void* d_ws, size_t ws_size,
                              hipStream_t stream)
{
    const float* x     = (const float*)d_in[0];
    const int* src0    = (const int*)d_in[1];
    const int* dst0    = (const int*)d_in[2];
    const int* eid0    = (const int*)d_in[3];
    const int* src1    = (const int*)d_in[4];
    const int* dst1    = (const int*)d_in[5];
    const int* eid1    = (const int*)d_in[6];
    const int* etype   = (const int*)d_in[7];
    const float* preW  = (const float*)d_in[8];
    const float* preb  = (const float*)d_in[9];
    const float* basis0 = (const float*)d_in[10];
    const float* comp0  = (const float*)d_in[11];
    const float* root0  = (const float*)d_in[12];
    const float* bias0  = (const float*)d_in[13];
    const float* g0    = (const float*)d_in[14];
    const float* be0   = (const float*)d_in[15];
    const float* basis1 = (const float*)d_in[16];
    const float* comp1  = (const float*)d_in[17];
    const float* root1  = (const float*)d_in[18];
    const float* bias1  = (const float*)d_in[19];
    const float* g1    = (const float*)d_in[20];
    const float* be1   = (const float*)d_in[21];
    const float* postW = (const float*)d_in[22];
    const float* postb = (const float*)d_in[23];
    float* out = (float*)d_out;

    char* ws = (char*)d_ws;
    size_t o = 0;
    auto alloc = [&](size_t bytes) { char* p = ws + o; o += (bytes + 255) & ~(size_t)255; return p; };
    u16* h0   = (u16*)alloc((size_t)N0C * DD * 2);
    u16* T0   = (u16*)alloc((size_t)4 * N1C * DD * 2);
    u16* h1   = (u16*)alloc((size_t)N1C * DD * 2);
    u16* T1   = (u16*)alloc((size_t)4 * N2C * DD * 2);
    u16* wt   = (u16*)alloc((size_t)12 * 16384 * 2);
    int* cnt0 = (int*)alloc((size_t)N1C * 4);
    int* cnt1 = (int*)alloc((size_t)N2C * 4);
    int* ep0  = (int*)alloc((size_t)N1C * CAP * 4);
    int* ep1  = (int*)alloc((size_t)N2C * CAP * 4);
    unsigned* r4 = (unsigned*)alloc((size_t)(ETOTC / 8) * 4);

    // wt layout: [0]=pre, [1..4]=basis0, [5]=root0, [6..9]=basis1, [10]=root1, [11]=post
    WtJob job;
    job.src[0] = preW;
    for (int b = 0; b < 4; ++b) job.src[1 + b] = basis0 + (size_t)b * 16384;
    job.src[5] = root0;
    for (int b = 0; b < 4; ++b) job.src[6 + b] = basis1 + (size_t)b * 16384;
    job.src[10] = root1;
    job.src[11] = postW;

    // K1: weight transpose + zero counters + etype nibble-pack
    prep_kernel<<<256, 256, 0, stream>>>(job, wt, cnt0, cnt1, etype, r4);
    // K2: fused fill (128 blocks, inline batched) + pre-GEMM (938 blocks)
    fillpre_kernel<<<ESB + (N0C + 127) / 128, 256, 0, stream>>>(
        x, src0, dst0, eid0, src1, dst1, eid1, r4,
        cnt0, cnt1, ep0, ep1, wt + 0 * 16384, preb, h0);
    // K3: agg layer 0 (1 row/wave, 7500 blocks)
    agg_kernel<<<(N1C + 3) / 4, 256, 0, stream>>>(h0, cnt0, ep0, comp0, T0, N1C);
    // K4: conv0 + LN + ReLU
    mfma_gemm_ln<<<(N1C + 31) / 32, 64, 0, stream>>>(
        T0, h0, wt + 1 * 16384, wt + 5 * 16384, bias0, g0, be0, h1, N1C);
    // K5: agg layer 1
    agg_kernel<<<(N2C + 3) / 4, 256, 0, stream>>>(h1, cnt1, ep1, comp1, T1, N2C);
    // K6: conv1 + LN + ReLU + post-GEMM (writes float out directly)
    gemm_post_kernel<<<(N2C + 31) / 32, 64, 0, stream>>>(
        T1, h1, wt + 6 * 16384, wt + 10 * 16384, bias1, g1, be1,
        wt + 11 * 16384, postb, out, N2C);
}